// Round 4
// baseline (576.038 us; speedup 1.0000x reference)
//
#include <hip/hip_runtime.h>

#define NN 50000
#define NE 1600000
#define DD 64
#define NPB 196          // nodes per bucket
#define HPB 98           // nodes per build_ell half-bucket block
#define NBKT 256         // buckets (NPB*NBKT = 50176 >= NN)
#define CHUNK 2500       // edges per bin block (640 blocks * 2500 = NE)
#define NBLK 640
#define SLOT 24          // LDS records per bucket: lambda=9.77, +4.5 sigma
#define SSTR 25          // LDS stride pad (R12-proven)
#define S1CAP 1024       // per-(bucket,shard) region: lambda=781, +8.7 sigma
#define SPCAP 512        // per-bucket global spill region
#define ELLW 80          // fixed records per node row (pad-to-16); P(deg>80)~1e-12
#define PSLOTS 64000     // perm slots (sum of class caps), 4000 fused blocks

typedef __attribute__((ext_vector_type(8))) short bf16x8;   // 8 bf16 = 4 VGPR
typedef __attribute__((ext_vector_type(4))) float f32x4;
typedef __attribute__((ext_vector_type(2))) float f32x2;

static __device__ __forceinline__ unsigned short f2bf(float f) {
    unsigned int u = __float_as_uint(f);
    unsigned int r = (u + 0x7FFFu + ((u >> 16) & 1u)) >> 16;   // RNE
    return (unsigned short)r;
}
static __device__ __forceinline__ float bf2f(unsigned short h) {
    return __uint_as_float((unsigned int)h << 16);
}
// pack 4 fp32 -> 4 x fp8-e4m3 (OCP, HW cvt)
static __device__ __forceinline__ unsigned int pk_fp8x4(float a, float b, float c, float d) {
    unsigned int p = __builtin_amdgcn_cvt_pk_fp8_f32(a, b, 0u, false);
    p = __builtin_amdgcn_cvt_pk_fp8_f32(c, d, p, true);
    return p;
}

// ---------------------------------------------------------------------------
// R15/R18 FUSED prep + binning (proven). Blocks 0..639: LDS-staged edge
// binning. Blocks 640..3764: x cast. Blocks 3765..3780: W cast.
// Record: .x = dst(16) | w_bf16<<16, .y = node-within-bucket.
// ---------------------------------------------------------------------------
__global__ __launch_bounds__(256) void prep_bin(
    const int* __restrict__ ei, const float* __restrict__ ew,
    int* __restrict__ gcur, int* __restrict__ gspillc,
    int2* __restrict__ buf1, int2* __restrict__ spill,
    const float* __restrict__ x, ushort* __restrict__ xb,
    unsigned int* __restrict__ xf8,
    const float* __restrict__ W1, const float* __restrict__ W2,
    ushort* __restrict__ W1b, ushort* __restrict__ W2b)
{
    __shared__ int2 slot[NBKT * SSTR];   // 50 KB
    __shared__ int  lcnt[NBKT];
    __shared__ int  lbase[NBKT];
    int tid = threadIdx.x;
    int blk = blockIdx.x;

    if (blk >= NBLK) {
        int pb = blk - NBLK;
        if (pb < 3125) {                   // 3125*256 = 800000 = NN*DD/4
            int i = pb * 256 + tid;
            float4 v = ((const float4*)x)[i];
            ushort4 o;
            o.x = f2bf(v.x); o.y = f2bf(v.y); o.z = f2bf(v.z); o.w = f2bf(v.w);
            ((ushort4*)xb)[i] = o;
            xf8[i] = pk_fp8x4(v.x, v.y, v.z, v.w);
        } else {                           // 16*256 = 4096 float4 groups
            int i = (pb - 3125) * 256 + tid;
            const float* src = (i < 2048) ? W1 : W2;
            ushort* dst = (i < 2048) ? W1b : W2b;
            int j = i & 2047;
            float4 v = ((const float4*)src)[j];
            ushort4 o;
            o.x = f2bf(v.x); o.y = f2bf(v.y); o.z = f2bf(v.z); o.w = f2bf(v.w);
            ((ushort4*)dst)[j] = o;
        }
        return;
    }

    int shard = blk & 7;
    for (int b = tid; b < NBKT; b += 256) lcnt[b] = 0;
    __syncthreads();

    // 4-wide edge loads: CHUNK/4 = 625 int4-groups per block
    int g0 = blk * (CHUNK / 4);            // int4-group base
    const int4*   s4 = (const int4*)ei;            // src words
    const int4*   d4 = ((const int4*)ei) + NE / 4; // dst words
    const float4* w4 = (const float4*)ew;
    for (int it = 0; it < 3; ++it) {
        int idx = it * 256 + tid;
        if (idx >= CHUNK / 4) break;
        int4 sv = s4[g0 + idx];
        int4 dv = d4[g0 + idx];
        float4 wv = w4[g0 + idx];
#pragma unroll
        for (int k = 0; k < 4; ++k) {
            int s = (k == 0) ? sv.x : (k == 1) ? sv.y : (k == 2) ? sv.z : sv.w;
            int d = (k == 0) ? dv.x : (k == 1) ? dv.y : (k == 2) ? dv.z : dv.w;
            float w = (k == 0) ? wv.x : (k == 1) ? wv.y : (k == 2) ? wv.z : wv.w;
            int bkt = s / NPB;
            int sloc = s - bkt * NPB;
            int2 rec = make_int2(d | ((int)f2bf(w) << 16), sloc);
            int pos = atomicAdd(&lcnt[bkt], 1);
            if (pos < SLOT) {
                slot[bkt * SSTR + pos] = rec;
            } else {
                int sp = atomicAdd(&gspillc[bkt], 1);
                if (sp < SPCAP) spill[bkt * SPCAP + sp] = rec;
            }
        }
    }
    __syncthreads();

    // one global reservation per (block,bucket); tid==bucket (256==NBKT)
    {
        int b = tid;
        int n = lcnt[b]; if (n > SLOT) n = SLOT;
        lcnt[b] = n;
        lbase[b] = (n > 0) ? atomicAdd(&gcur[b * 8 + shard], n) : 0;
    }
    __syncthreads();

    // R18 flush: 16-lane group per bucket, 4 buckets per wave-iteration.
    int wave = tid >> 6, lane = tid & 63;
    int grp = lane >> 4, l16 = lane & 15;
#pragma unroll 4
    for (int jj = 0; jj < 16; ++jj) {
        int b = wave * 64 + jj * 4 + grp;
        int n = lcnt[b];
        int base = lbase[b];
        int2* dst = &buf1[((size_t)b * 8 + shard) * S1CAP];
        if (l16 < n) {
            int2 rec = slot[b * SSTR + l16];
            int p = base + l16;
            if (p < S1CAP) dst[p] = rec;
            else { int sp = atomicAdd(&gspillc[b], 1);
                   if (sp < SPCAP) spill[b * SPCAP + sp] = rec; }
        }
        if (l16 + 16 < n) {                 // n <= 24, so only lanes 0..7
            int2 rec = slot[b * SSTR + l16 + 16];
            int p = base + l16 + 16;
            if (p < S1CAP) dst[p] = rec;
            else { int sp = atomicAdd(&gspillc[b], 1);
                   if (sp < SPCAP) spill[b * SPCAP + sp] = rec; }
        }
    }
}

// ---------------------------------------------------------------------------
// R18 ELL build + R19 degree-class perm. Grid 512 = 2 blocks per bucket
// (node-halves). Tail: each node is counting-sorted by ceil16(deg) class
// into a fixed-region perm array (one global atomic per node). Class caps
// are +30 sigma for the Poisson(32) degree distribution; overflow falls to
// a mixed class-5 region. fused_layer reads 16 same-class nodes per block
// -> barrier imbalance (max-of-16 degrees vs own degree) collapses.
// perm is memset to -1 (0xFF) before this kernel; clsCnt to 0.
// ---------------------------------------------------------------------------
__global__ __launch_bounds__(1024) void build_ell(
    const int* __restrict__ gcur, const int2* __restrict__ buf1,
    const int* __restrict__ gspillc, const int2* __restrict__ spill,
    unsigned int* __restrict__ csr, int* __restrict__ cnt,
    int* __restrict__ clsCnt, int* __restrict__ perm)
{
    __shared__ int cur[HPB];
    __shared__ int cnts[9];
    int tid = threadIdx.x;
    int bkt  = blockIdx.x >> 1;
    int nlo  = (blockIdx.x & 1) * HPB;      // this block owns nodes [nlo, nlo+98)

    if (tid < HPB) cur[tid] = 0;
    if (tid >= 128 && tid < 137) {          // parallel count prefetch
        int sh = tid - 128;
        int n = (sh < 8) ? gcur[bkt * 8 + sh] : gspillc[bkt];
        int cap = (sh < 8) ? S1CAP : SPCAP;
        cnts[sh] = n < cap ? n : cap;
    }
    __syncthreads();

    // 8 shards concurrently: 128 threads each
    {
        int sh = tid >> 7, lt = tid & 127;
        int n = cnts[sh];
        const int2* rp = buf1 + ((size_t)bkt * 8 + sh) * S1CAP;
        for (int i = lt; i < n; i += 128) {
            int2 r = rp[i];
            int node = r.y - nlo;
            if ((unsigned)node < HPB) {
                int pos = atomicAdd(&cur[node], 1);
                if (pos < ELLW)
                    csr[((size_t)(bkt * NPB + r.y)) * ELLW + pos] = (unsigned int)r.x;
            }
        }
    }
    // spill region: all threads
    {
        int n = cnts[8];
        const int2* rp = spill + (size_t)bkt * SPCAP;
        for (int i = tid; i < n; i += 1024) {
            int2 r = rp[i];
            int node = r.y - nlo;
            if ((unsigned)node < HPB) {
                int pos = atomicAdd(&cur[node], 1);
                if (pos < ELLW)
                    csr[((size_t)(bkt * NPB + r.y)) * ELLW + pos] = (unsigned int)r.x;
            }
        }
    }
    __syncthreads();

    if (tid < HPB) {
        int node = bkt * NPB + nlo + tid;
        if (node < NN) {
            int deg = cur[tid];
            cnt[node] = deg;
            int c = deg < ELLW ? deg : ELLW;
            int c16 = (c + 15) & ~15;          // <= 80 always
            for (int p = c; p < c16; ++p)
                csr[(size_t)node * ELLW + p] = 0u;

            // degree-class perm placement (R19)
            int cls = (deg <= 16) ? 0 : (deg <= 32) ? 1 : (deg <= 48) ? 2
                    : (deg <= 64) ? 3 : 4;
            int cap = (cls == 0) ? 2048 : (cls == 1) ? 30720
                    : (cls == 2) ? 26624 : (cls == 3) ? 2048 : 512;
            int cbs = (cls == 0) ? 0 : (cls == 1) ? 2048
                    : (cls == 2) ? 32768 : (cls == 3) ? 59392 : 61440;
            int pos = atomicAdd(&clsCnt[cls], 1);
            if (pos >= cap) {                   // stat-impossible fallback
                cbs = 61952; cap = 2048;
                pos = atomicAdd(&clsCnt[5], 1);
            }
            if (pos < cap) perm[cbs + pos] = node;
        }
    }
}

// ---------------------------------------------------------------------------
// R19 FUSED layer: block = 512 thr = 8 waves = 16 SAME-DEGREE-CLASS nodes
// via perm indirection (2 per wave, interleaved chains). Empty perm slots
// (-1) are masked: zero self-row, deg 0, store skipped via LDS nid table.
// float2 accumulators -> v_pk_fma_f32 (halves FMA count in hot loop).
// Phase 2 (R7 layouts): waves 0-3 = one 16-col tile, 4 MFMAs.
// ---------------------------------------------------------------------------
__global__ __launch_bounds__(512) void fused_layer(
    const ushort* __restrict__ Xb,          // self features bf16 [NN][64]
    const unsigned int* __restrict__ f8,    // gather table fp8, 16 uints/row
    const int* __restrict__ cnt, const unsigned int* __restrict__ csr,
    const int* __restrict__ perm,
    const ushort* __restrict__ Wb, const float* __restrict__ bias,
    float* __restrict__ out, ushort* __restrict__ outb,
    unsigned char* __restrict__ outf8)
{
    __shared__ ushort xL[16][72];
    __shared__ ushort aggL[16][72];
    __shared__ int nid[16];
    int tid = threadIdx.x;
    int wave = tid >> 6, lane = tid & 63;   // wave in 0..7
    int g = lane >> 4, l16 = lane & 15;
    int base = blockIdx.x * 16;
    int nodeA = perm[base + wave];          // tile rows 0..7
    int nodeB = perm[base + wave + 8];      // tile rows 8..15
    if (lane == 0) { nid[wave] = nodeA; nid[wave + 8] = nodeB; }

    // stage self rows (zero for empty slots)
    if (lane < 16) {
        ushort4 z = make_ushort4(0, 0, 0, 0);
        *(ushort4*)&xL[wave][l16 * 4] = (nodeA >= 0)
            ? *(const ushort4*)&Xb[(size_t)nodeA * DD + l16 * 4] : z;
        *(ushort4*)&xL[wave + 8][l16 * 4] = (nodeB >= 0)
            ? *(const ushort4*)&Xb[(size_t)nodeB * DD + l16 * 4] : z;
    }

    // ---- phase 1: aggregate two nodes per wave, interleaved ----
    int ndA = (nodeA >= 0) ? cnt[nodeA] : 0;
    int ndB = (nodeB >= 0) ? cnt[nodeB] : 0;
    int nA = ndA < ELLW ? ndA : ELLW;
    int nB = ndB < ELLW ? ndB : ELLW;
    int nA16 = (nA + 15) & ~15;             // rows zero-padded to here
    int nB16 = (nB + 15) & ~15;
    int imax = nA16 > nB16 ? nA16 : nB16;
    const unsigned int* __restrict__ rpA = csr + (size_t)(nodeA > 0 ? nodeA : 0) * ELLW;
    const unsigned int* __restrict__ rpB = csr + (size_t)(nodeB > 0 ? nodeB : 0) * ELLW;
    f32x2 sA01 = {0.f, 0.f}, sA23 = {0.f, 0.f};
    f32x2 sB01 = {0.f, 0.f}, sB23 = {0.f, 0.f};

    for (int i = 0; i < imax; i += 16) {
        // issue both ELL row reads first (independent)
        uint4 rA, rB;
        bool doA = i < nA16, doB = i < nB16;
        if (doA) rA = *(const uint4*)(rpA + i + g * 4);
        if (doB) rB = *(const uint4*)(rpB + i + g * 4);
        if (doA) {
            unsigned int v0 = f8[(rA.x & 0xFFFF) * 16 + l16];
            unsigned int v1 = f8[(rA.y & 0xFFFF) * 16 + l16];
            unsigned int v2 = f8[(rA.z & 0xFFFF) * 16 + l16];
            unsigned int v3 = f8[(rA.w & 0xFFFF) * 16 + l16];
            float w0 = bf2f((unsigned short)(rA.x >> 16));
            float w1 = bf2f((unsigned short)(rA.y >> 16));
            float w2 = bf2f((unsigned short)(rA.z >> 16));
            float w3 = bf2f((unsigned short)(rA.w >> 16));
            f32x2 lo, hi, wp;
            lo = __builtin_amdgcn_cvt_pk_f32_fp8(v0, false);
            hi = __builtin_amdgcn_cvt_pk_f32_fp8(v0, true);
            wp = (f32x2){w0, w0}; sA01 += wp * lo; sA23 += wp * hi;
            lo = __builtin_amdgcn_cvt_pk_f32_fp8(v1, false);
            hi = __builtin_amdgcn_cvt_pk_f32_fp8(v1, true);
            wp = (f32x2){w1, w1}; sA01 += wp * lo; sA23 += wp * hi;
            lo = __builtin_amdgcn_cvt_pk_f32_fp8(v2, false);
            hi = __builtin_amdgcn_cvt_pk_f32_fp8(v2, true);
            wp = (f32x2){w2, w2}; sA01 += wp * lo; sA23 += wp * hi;
            lo = __builtin_amdgcn_cvt_pk_f32_fp8(v3, false);
            hi = __builtin_amdgcn_cvt_pk_f32_fp8(v3, true);
            wp = (f32x2){w3, w3}; sA01 += wp * lo; sA23 += wp * hi;
        }
        if (doB) {
            unsigned int v0 = f8[(rB.x & 0xFFFF) * 16 + l16];
            unsigned int v1 = f8[(rB.y & 0xFFFF) * 16 + l16];
            unsigned int v2 = f8[(rB.z & 0xFFFF) * 16 + l16];
            unsigned int v3 = f8[(rB.w & 0xFFFF) * 16 + l16];
            float w0 = bf2f((unsigned short)(rB.x >> 16));
            float w1 = bf2f((unsigned short)(rB.y >> 16));
            float w2 = bf2f((unsigned short)(rB.z >> 16));
            float w3 = bf2f((unsigned short)(rB.w >> 16));
            f32x2 lo, hi, wp;
            lo = __builtin_amdgcn_cvt_pk_f32_fp8(v0, false);
            hi = __builtin_amdgcn_cvt_pk_f32_fp8(v0, true);
            wp = (f32x2){w0, w0}; sB01 += wp * lo; sB23 += wp * hi;
            lo = __builtin_amdgcn_cvt_pk_f32_fp8(v1, false);
            hi = __builtin_amdgcn_cvt_pk_f32_fp8(v1, true);
            wp = (f32x2){w1, w1}; sB01 += wp * lo; sB23 += wp * hi;
            lo = __builtin_amdgcn_cvt_pk_f32_fp8(v2, false);
            hi = __builtin_amdgcn_cvt_pk_f32_fp8(v2, true);
            wp = (f32x2){w2, w2}; sB01 += wp * lo; sB23 += wp * hi;
            lo = __builtin_amdgcn_cvt_pk_f32_fp8(v3, false);
            hi = __builtin_amdgcn_cvt_pk_f32_fp8(v3, true);
            wp = (f32x2){w3, w3}; sB01 += wp * lo; sB23 += wp * hi;
        }
    }

    float aA0 = sA01.x, aA1 = sA01.y, aA2 = sA23.x, aA3 = sA23.y;
    float aB0 = sB01.x, aB1 = sB01.y, aB2 = sB23.x, aB3 = sB23.y;
    aA0 += __shfl_xor(aA0, 16); aA0 += __shfl_xor(aA0, 32);
    aA1 += __shfl_xor(aA1, 16); aA1 += __shfl_xor(aA1, 32);
    aA2 += __shfl_xor(aA2, 16); aA2 += __shfl_xor(aA2, 32);
    aA3 += __shfl_xor(aA3, 16); aA3 += __shfl_xor(aA3, 32);
    aB0 += __shfl_xor(aB0, 16); aB0 += __shfl_xor(aB0, 32);
    aB1 += __shfl_xor(aB1, 16); aB1 += __shfl_xor(aB1, 32);
    aB2 += __shfl_xor(aB2, 16); aB2 += __shfl_xor(aB2, 32);
    aB3 += __shfl_xor(aB3, 16); aB3 += __shfl_xor(aB3, 32);

    if (lane < 16) {
        float dmA = (float)(ndA > 1 ? ndA : 1);
        float dmB = (float)(ndB > 1 ? ndB : 1);
        ushort4 oA, oB;
        oA.x = f2bf(aA0 / dmA); oA.y = f2bf(aA1 / dmA);
        oA.z = f2bf(aA2 / dmA); oA.w = f2bf(aA3 / dmA);
        oB.x = f2bf(aB0 / dmB); oB.y = f2bf(aB1 / dmB);
        oB.z = f2bf(aB2 / dmB); oB.w = f2bf(aB3 / dmB);
        *(ushort4*)&aggL[wave][l16 * 4] = oA;
        *(ushort4*)&aggL[wave + 8][l16 * 4] = oB;
    }
    __syncthreads();

    // ---- phase 2: GEMM (waves 0-3; wave = col tile) ----
    if (wave < 4) {
        f32x4 acc = (f32x4){0.f, 0.f, 0.f, 0.f};
#pragma unroll
        for (int ki = 0; ki < 4; ++ki) {
            const ushort* ap = (ki < 2) ? &xL[l16][ki * 32 + g * 8]
                                        : &aggL[l16][(ki - 2) * 32 + g * 8];
            bf16x8 af = *(const bf16x8*)ap;
            bf16x8 bfrag = *(const bf16x8*)&Wb[(size_t)(wave * 16 + l16) * 128 + ki * 32 + g * 8];
            acc = __builtin_amdgcn_mfma_f32_16x16x32_bf16(af, bfrag, acc, 0, 0, 0);
        }
        int col = wave * 16 + l16;
        float bv = bias[col];
#pragma unroll
        for (int r = 0; r < 4; ++r) {
            int gn = nid[g * 4 + r];       // C/D: col=lane&15, row=quad*4+reg
            if (gn >= 0) {
                float v = fmaxf(acc[r] + bv, 0.f);
                if (out)  out[(size_t)gn * DD + col] = v;
                if (outb) outb[(size_t)gn * DD + col] = f2bf(v);
                if (outf8) {
                    unsigned int p = __builtin_amdgcn_cvt_pk_fp8_f32(v, v, 0u, false);
                    outf8[(size_t)gn * DD + col] = (unsigned char)(p & 0xFFu);
                }
            }
        }
    }
}

// ---------------------------------------------------------------------------
extern "C" void kernel_launch(void* const* d_in, const int* in_sizes, int n_in,
                              void* d_out, int out_size, void* d_ws, size_t ws_size,
                              hipStream_t stream)
{
    const float* x  = (const float*)d_in[0];
    const int*   ei = (const int*)d_in[1];
    const float* ew = (const float*)d_in[2];
    const float* W1 = (const float*)d_in[3];
    const float* b1 = (const float*)d_in[4];
    const float* W2 = (const float*)d_in[5];
    const float* b2 = (const float*)d_in[6];
    float* out = (float*)d_out;

    // workspace layout, ~53.6 MB (16B-aligned offsets)
    char* ws = (char*)d_ws;
    int*          gcur    = (int*)ws;                          //      8,192 B
    int*          gspillc = (int*)(ws + 8192);                 //      1,024 B
    int*          clsCnt  = (int*)(ws + 9216);                 //         64 B
    int*          perm    = (int*)(ws + 9280);                 //    256,000 B
    int2*         buf1    = (int2*)(ws + 265280);              // 16,777,216 B
    int2*         spill   = (int2*)(ws + 17042496);            //  1,048,576 B
    unsigned int* csr     = (unsigned int*)(ws + 18091072);    // 16,056,320 B (ELL 80/node)
    int*          cnt     = (int*)(ws + 34147392);             //    200,704 B
    ushort*       xb      = (ushort*)(ws + 34348096);          //  6,400,000 B
    ushort*       h1b     = (ushort*)(ws + 40748096);          //  6,400,000 B
    ushort*       W1b     = (ushort*)(ws + 47148096);          //     16,384 B
    ushort*       W2b     = (ushort*)(ws + 47164480);          //     16,384 B
    unsigned int* xf8     = (unsigned int*)(ws + 47180864);    //  3,200,000 B
    unsigned char* h1f8   = (unsigned char*)(ws + 50380864);   //  3,200,000 B

    hipMemsetAsync(gcur, 0, 9280, stream);        // gcur + gspillc + clsCnt
    hipMemsetAsync(perm, 0xFF, 256000, stream);   // perm = -1 sentinels

    prep_bin<<<NBLK + 3141, 256, 0, stream>>>(ei, ew, gcur, gspillc, buf1, spill,
                                              x, xb, xf8, W1, W2, W1b, W2b);
    build_ell<<<NBKT * 2, 1024, 0, stream>>>(gcur, buf1, gspillc, spill, csr, cnt,
                                             clsCnt, perm);

    // layer 1: gather fp8(x), self bf16(x) -> h1b + h1f8
    fused_layer<<<PSLOTS / 16, 512, 0, stream>>>(xb, xf8, cnt, csr, perm, W1b, b1,
                                                 nullptr, h1b, h1f8);
    // layer 2: gather fp8(h1), self bf16(h1) -> out
    fused_layer<<<PSLOTS / 16, 512, 0, stream>>>(h1b, (const unsigned int*)h1f8,
                                                 cnt, csr, perm, W2b, b2,
                                                 out, nullptr, nullptr);
}

// Round 5
// 188.928 us; speedup vs baseline: 3.0490x; 3.0490x over previous
//
#include <hip/hip_runtime.h>

#define NN 50000
#define NE 1600000
#define DD 64
#define NPB 196          // nodes per bucket
#define HPB 98           // nodes per build_ell half-bucket block
#define NBKT 256         // buckets (NPB*NBKT = 50176 >= NN)
#define CHUNK 2500       // edges per bin block (640 blocks * 2500 = NE)
#define NBLK 640
#define SLOT 24          // LDS records per bucket: lambda=9.77, +4.5 sigma
#define SSTR 25          // LDS stride pad (R12-proven)
#define S1CAP 1024       // per-(bucket,shard) region: lambda=781, +8.7 sigma
#define SPCAP 512        // per-bucket global spill region
#define ELLW 80          // fixed records per node row (pad-to-16); P(deg>80)~1e-12
#define PSLOTS 53392     // perm slots (sum of class caps), 3337 fused blocks

typedef __attribute__((ext_vector_type(8))) short bf16x8;   // 8 bf16 = 4 VGPR
typedef __attribute__((ext_vector_type(4))) float f32x4;
typedef __attribute__((ext_vector_type(2))) float f32x2;

static __device__ __forceinline__ unsigned short f2bf(float f) {
    unsigned int u = __float_as_uint(f);
    unsigned int r = (u + 0x7FFFu + ((u >> 16) & 1u)) >> 16;   // RNE
    return (unsigned short)r;
}
static __device__ __forceinline__ float bf2f(unsigned short h) {
    return __uint_as_float((unsigned int)h << 16);
}
// pack 4 fp32 -> 4 x fp8-e4m3 (OCP, HW cvt)
static __device__ __forceinline__ unsigned int pk_fp8x4(float a, float b, float c, float d) {
    unsigned int p = __builtin_amdgcn_cvt_pk_fp8_f32(a, b, 0u, false);
    p = __builtin_amdgcn_cvt_pk_fp8_f32(c, d, p, true);
    return p;
}

// degree-class geometry (R20): caps are +9 sigma on the Binomial class counts
// cls0 deg<=16 (~150 nodes), cls1 17-32 (~27.2K), cls2 33-48 (~22.6K),
// cls3 49-64 (~140), cls4 65-80 (~0), cls5 = overflow fallback.
__device__ __constant__ int cCap[6]  = {512, 28192, 23600, 512, 64, 512};
__device__ __constant__ int cBase[6] = {0, 512, 28704, 52304, 52816, 52880};

// ---------------------------------------------------------------------------
// R15/R18 FUSED prep + binning (proven). Blocks 0..639: LDS-staged edge
// binning. Blocks 640..3764: x cast. Blocks 3765..3780: W cast.
// Record: .x = dst(16) | w_bf16<<16, .y = node-within-bucket.
// ---------------------------------------------------------------------------
__global__ __launch_bounds__(256) void prep_bin(
    const int* __restrict__ ei, const float* __restrict__ ew,
    int* __restrict__ gcur, int* __restrict__ gspillc,
    int2* __restrict__ buf1, int2* __restrict__ spill,
    const float* __restrict__ x, ushort* __restrict__ xb,
    unsigned int* __restrict__ xf8,
    const float* __restrict__ W1, const float* __restrict__ W2,
    ushort* __restrict__ W1b, ushort* __restrict__ W2b)
{
    __shared__ int2 slot[NBKT * SSTR];   // 50 KB
    __shared__ int  lcnt[NBKT];
    __shared__ int  lbase[NBKT];
    int tid = threadIdx.x;
    int blk = blockIdx.x;

    if (blk >= NBLK) {
        int pb = blk - NBLK;
        if (pb < 3125) {                   // 3125*256 = 800000 = NN*DD/4
            int i = pb * 256 + tid;
            float4 v = ((const float4*)x)[i];
            ushort4 o;
            o.x = f2bf(v.x); o.y = f2bf(v.y); o.z = f2bf(v.z); o.w = f2bf(v.w);
            ((ushort4*)xb)[i] = o;
            xf8[i] = pk_fp8x4(v.x, v.y, v.z, v.w);
        } else {                           // 16*256 = 4096 float4 groups
            int i = (pb - 3125) * 256 + tid;
            const float* src = (i < 2048) ? W1 : W2;
            ushort* dst = (i < 2048) ? W1b : W2b;
            int j = i & 2047;
            float4 v = ((const float4*)src)[j];
            ushort4 o;
            o.x = f2bf(v.x); o.y = f2bf(v.y); o.z = f2bf(v.z); o.w = f2bf(v.w);
            ((ushort4*)dst)[j] = o;
        }
        return;
    }

    int shard = blk & 7;
    for (int b = tid; b < NBKT; b += 256) lcnt[b] = 0;
    __syncthreads();

    // 4-wide edge loads: CHUNK/4 = 625 int4-groups per block
    int g0 = blk * (CHUNK / 4);            // int4-group base
    const int4*   s4 = (const int4*)ei;            // src words
    const int4*   d4 = ((const int4*)ei) + NE / 4; // dst words
    const float4* w4 = (const float4*)ew;
    for (int it = 0; it < 3; ++it) {
        int idx = it * 256 + tid;
        if (idx >= CHUNK / 4) break;
        int4 sv = s4[g0 + idx];
        int4 dv = d4[g0 + idx];
        float4 wv = w4[g0 + idx];
#pragma unroll
        for (int k = 0; k < 4; ++k) {
            int s = (k == 0) ? sv.x : (k == 1) ? sv.y : (k == 2) ? sv.z : sv.w;
            int d = (k == 0) ? dv.x : (k == 1) ? dv.y : (k == 2) ? dv.z : dv.w;
            float w = (k == 0) ? wv.x : (k == 1) ? wv.y : (k == 2) ? wv.z : wv.w;
            int bkt = s / NPB;
            int sloc = s - bkt * NPB;
            int2 rec = make_int2(d | ((int)f2bf(w) << 16), sloc);
            int pos = atomicAdd(&lcnt[bkt], 1);
            if (pos < SLOT) {
                slot[bkt * SSTR + pos] = rec;
            } else {
                int sp = atomicAdd(&gspillc[bkt], 1);
                if (sp < SPCAP) spill[bkt * SPCAP + sp] = rec;
            }
        }
    }
    __syncthreads();

    // one global reservation per (block,bucket); tid==bucket (256==NBKT)
    {
        int b = tid;
        int n = lcnt[b]; if (n > SLOT) n = SLOT;
        lcnt[b] = n;
        lbase[b] = (n > 0) ? atomicAdd(&gcur[b * 8 + shard], n) : 0;
    }
    __syncthreads();

    // R18 flush: 16-lane group per bucket, 4 buckets per wave-iteration.
    int wave = tid >> 6, lane = tid & 63;
    int grp = lane >> 4, l16 = lane & 15;
#pragma unroll 4
    for (int jj = 0; jj < 16; ++jj) {
        int b = wave * 64 + jj * 4 + grp;
        int n = lcnt[b];
        int base = lbase[b];
        int2* dst = &buf1[((size_t)b * 8 + shard) * S1CAP];
        if (l16 < n) {
            int2 rec = slot[b * SSTR + l16];
            int p = base + l16;
            if (p < S1CAP) dst[p] = rec;
            else { int sp = atomicAdd(&gspillc[b], 1);
                   if (sp < SPCAP) spill[b * SPCAP + sp] = rec; }
        }
        if (l16 + 16 < n) {                 // n <= 24, so only lanes 0..7
            int2 rec = slot[b * SSTR + l16 + 16];
            int p = base + l16 + 16;
            if (p < S1CAP) dst[p] = rec;
            else { int sp = atomicAdd(&gspillc[b], 1);
                   if (sp < SPCAP) spill[b * SPCAP + sp] = rec; }
        }
    }
}

// ---------------------------------------------------------------------------
// R18 ELL build + R20 degree-class perm with PER-BLOCK reservation.
// R19's per-node global atomics on 6 shared counters serialized at the
// coherence point (50K x ~13ns = 394us). Fix: LDS histogram of the block's
// <=98 nodes, ONE global atomicAdd per non-empty class per block (<=3072
// total), then perm[base+lpos]. Grid 512 = 2 blocks per bucket.
// perm memset to -1 and clsCnt to 0 before this kernel.
// ---------------------------------------------------------------------------
__global__ __launch_bounds__(1024) void build_ell(
    const int* __restrict__ gcur, const int2* __restrict__ buf1,
    const int* __restrict__ gspillc, const int2* __restrict__ spill,
    unsigned int* __restrict__ csr, int* __restrict__ cnt,
    int* __restrict__ clsCnt, int* __restrict__ perm)
{
    __shared__ int cur[HPB];
    __shared__ int cnts[9];
    __shared__ int lcls[6];
    __shared__ int lbase6[6];
    int tid = threadIdx.x;
    int bkt  = blockIdx.x >> 1;
    int nlo  = (blockIdx.x & 1) * HPB;      // this block owns nodes [nlo, nlo+98)

    if (tid < HPB) cur[tid] = 0;
    if (tid >= 128 && tid < 137) {          // parallel count prefetch
        int sh = tid - 128;
        int n = (sh < 8) ? gcur[bkt * 8 + sh] : gspillc[bkt];
        int cap = (sh < 8) ? S1CAP : SPCAP;
        cnts[sh] = n < cap ? n : cap;
    }
    if (tid >= 160 && tid < 166) lcls[tid - 160] = 0;
    __syncthreads();

    // 8 shards concurrently: 128 threads each
    {
        int sh = tid >> 7, lt = tid & 127;
        int n = cnts[sh];
        const int2* rp = buf1 + ((size_t)bkt * 8 + sh) * S1CAP;
        for (int i = lt; i < n; i += 128) {
            int2 r = rp[i];
            int node = r.y - nlo;
            if ((unsigned)node < HPB) {
                int pos = atomicAdd(&cur[node], 1);
                if (pos < ELLW)
                    csr[((size_t)(bkt * NPB + r.y)) * ELLW + pos] = (unsigned int)r.x;
            }
        }
    }
    // spill region: all threads
    {
        int n = cnts[8];
        const int2* rp = spill + (size_t)bkt * SPCAP;
        for (int i = tid; i < n; i += 1024) {
            int2 r = rp[i];
            int node = r.y - nlo;
            if ((unsigned)node < HPB) {
                int pos = atomicAdd(&cur[node], 1);
                if (pos < ELLW)
                    csr[((size_t)(bkt * NPB + r.y)) * ELLW + pos] = (unsigned int)r.x;
            }
        }
    }
    __syncthreads();

    // degree finalize + pad + LDS class histogram
    int node = bkt * NPB + nlo + tid;
    int cls = -1, lpos = 0;
    if (tid < HPB && node < NN) {
        int deg = cur[tid];
        cnt[node] = deg;
        int c = deg < ELLW ? deg : ELLW;
        int c16 = (c + 15) & ~15;          // <= 80 always
        for (int p = c; p < c16; ++p)
            csr[(size_t)node * ELLW + p] = 0u;
        cls = (deg <= 16) ? 0 : (deg <= 32) ? 1 : (deg <= 48) ? 2
            : (deg <= 64) ? 3 : 4;
        lpos = atomicAdd(&lcls[cls], 1);   // LDS atomic, cheap
    }
    __syncthreads();

    if (tid < 6) {                         // one global reservation per class
        int n = lcls[tid];
        lbase6[tid] = (n > 0) ? atomicAdd(&clsCnt[tid], n) : 0;
    }
    __syncthreads();

    if (cls >= 0) {
        int pos = lbase6[cls] + lpos;
        if (pos < cCap[cls]) {
            perm[cBase[cls] + pos] = node;
        } else {                           // stat-impossible overflow
            int p2 = atomicAdd(&clsCnt[5], 1);
            if (p2 < cCap[5]) perm[cBase[5] + p2] = node;
        }
    }
}

// ---------------------------------------------------------------------------
// R19/R20 FUSED layer: block = 512 thr = 8 waves = 16 SAME-DEGREE-CLASS
// nodes via perm indirection (2 per wave, interleaved chains). Empty perm
// slots (-1): zero self-row, deg 0, stores masked via LDS nid table.
// float2 accumulators -> v_pk_fma_f32. Phase 2 (R7 layouts) unchanged.
// ---------------------------------------------------------------------------
__global__ __launch_bounds__(512) void fused_layer(
    const ushort* __restrict__ Xb,          // self features bf16 [NN][64]
    const unsigned int* __restrict__ f8,    // gather table fp8, 16 uints/row
    const int* __restrict__ cnt, const unsigned int* __restrict__ csr,
    const int* __restrict__ perm,
    const ushort* __restrict__ Wb, const float* __restrict__ bias,
    float* __restrict__ out, ushort* __restrict__ outb,
    unsigned char* __restrict__ outf8)
{
    __shared__ ushort xL[16][72];
    __shared__ ushort aggL[16][72];
    __shared__ int nid[16];
    int tid = threadIdx.x;
    int wave = tid >> 6, lane = tid & 63;   // wave in 0..7
    int g = lane >> 4, l16 = lane & 15;
    int base = blockIdx.x * 16;
    int nodeA = perm[base + wave];          // tile rows 0..7
    int nodeB = perm[base + wave + 8];      // tile rows 8..15
    if (lane == 0) { nid[wave] = nodeA; nid[wave + 8] = nodeB; }

    // stage self rows (zero for empty slots)
    if (lane < 16) {
        ushort4 z = make_ushort4(0, 0, 0, 0);
        *(ushort4*)&xL[wave][l16 * 4] = (nodeA >= 0)
            ? *(const ushort4*)&Xb[(size_t)nodeA * DD + l16 * 4] : z;
        *(ushort4*)&xL[wave + 8][l16 * 4] = (nodeB >= 0)
            ? *(const ushort4*)&Xb[(size_t)nodeB * DD + l16 * 4] : z;
    }

    // ---- phase 1: aggregate two nodes per wave, interleaved ----
    int ndA = (nodeA >= 0) ? cnt[nodeA] : 0;
    int ndB = (nodeB >= 0) ? cnt[nodeB] : 0;
    int nA = ndA < ELLW ? ndA : ELLW;
    int nB = ndB < ELLW ? ndB : ELLW;
    int nA16 = (nA + 15) & ~15;             // rows zero-padded to here
    int nB16 = (nB + 15) & ~15;
    int imax = nA16 > nB16 ? nA16 : nB16;
    const unsigned int* __restrict__ rpA = csr + (size_t)(nodeA >= 0 ? nodeA : 0) * ELLW;
    const unsigned int* __restrict__ rpB = csr + (size_t)(nodeB >= 0 ? nodeB : 0) * ELLW;
    f32x2 sA01 = {0.f, 0.f}, sA23 = {0.f, 0.f};
    f32x2 sB01 = {0.f, 0.f}, sB23 = {0.f, 0.f};

    for (int i = 0; i < imax; i += 16) {
        // issue both ELL row reads first (independent)
        uint4 rA, rB;
        bool doA = i < nA16, doB = i < nB16;
        if (doA) rA = *(const uint4*)(rpA + i + g * 4);
        if (doB) rB = *(const uint4*)(rpB + i + g * 4);
        if (doA) {
            unsigned int v0 = f8[(rA.x & 0xFFFF) * 16 + l16];
            unsigned int v1 = f8[(rA.y & 0xFFFF) * 16 + l16];
            unsigned int v2 = f8[(rA.z & 0xFFFF) * 16 + l16];
            unsigned int v3 = f8[(rA.w & 0xFFFF) * 16 + l16];
            float w0 = bf2f((unsigned short)(rA.x >> 16));
            float w1 = bf2f((unsigned short)(rA.y >> 16));
            float w2 = bf2f((unsigned short)(rA.z >> 16));
            float w3 = bf2f((unsigned short)(rA.w >> 16));
            f32x2 lo, hi, wp;
            lo = __builtin_amdgcn_cvt_pk_f32_fp8(v0, false);
            hi = __builtin_amdgcn_cvt_pk_f32_fp8(v0, true);
            wp = (f32x2){w0, w0}; sA01 += wp * lo; sA23 += wp * hi;
            lo = __builtin_amdgcn_cvt_pk_f32_fp8(v1, false);
            hi = __builtin_amdgcn_cvt_pk_f32_fp8(v1, true);
            wp = (f32x2){w1, w1}; sA01 += wp * lo; sA23 += wp * hi;
            lo = __builtin_amdgcn_cvt_pk_f32_fp8(v2, false);
            hi = __builtin_amdgcn_cvt_pk_f32_fp8(v2, true);
            wp = (f32x2){w2, w2}; sA01 += wp * lo; sA23 += wp * hi;
            lo = __builtin_amdgcn_cvt_pk_f32_fp8(v3, false);
            hi = __builtin_amdgcn_cvt_pk_f32_fp8(v3, true);
            wp = (f32x2){w3, w3}; sA01 += wp * lo; sA23 += wp * hi;
        }
        if (doB) {
            unsigned int v0 = f8[(rB.x & 0xFFFF) * 16 + l16];
            unsigned int v1 = f8[(rB.y & 0xFFFF) * 16 + l16];
            unsigned int v2 = f8[(rB.z & 0xFFFF) * 16 + l16];
            unsigned int v3 = f8[(rB.w & 0xFFFF) * 16 + l16];
            float w0 = bf2f((unsigned short)(rB.x >> 16));
            float w1 = bf2f((unsigned short)(rB.y >> 16));
            float w2 = bf2f((unsigned short)(rB.z >> 16));
            float w3 = bf2f((unsigned short)(rB.w >> 16));
            f32x2 lo, hi, wp;
            lo = __builtin_amdgcn_cvt_pk_f32_fp8(v0, false);
            hi = __builtin_amdgcn_cvt_pk_f32_fp8(v0, true);
            wp = (f32x2){w0, w0}; sB01 += wp * lo; sB23 += wp * hi;
            lo = __builtin_amdgcn_cvt_pk_f32_fp8(v1, false);
            hi = __builtin_amdgcn_cvt_pk_f32_fp8(v1, true);
            wp = (f32x2){w1, w1}; sB01 += wp * lo; sB23 += wp * hi;
            lo = __builtin_amdgcn_cvt_pk_f32_fp8(v2, false);
            hi = __builtin_amdgcn_cvt_pk_f32_fp8(v2, true);
            wp = (f32x2){w2, w2}; sB01 += wp * lo; sB23 += wp * hi;
            lo = __builtin_amdgcn_cvt_pk_f32_fp8(v3, false);
            hi = __builtin_amdgcn_cvt_pk_f32_fp8(v3, true);
            wp = (f32x2){w3, w3}; sB01 += wp * lo; sB23 += wp * hi;
        }
    }

    float aA0 = sA01.x, aA1 = sA01.y, aA2 = sA23.x, aA3 = sA23.y;
    float aB0 = sB01.x, aB1 = sB01.y, aB2 = sB23.x, aB3 = sB23.y;
    aA0 += __shfl_xor(aA0, 16); aA0 += __shfl_xor(aA0, 32);
    aA1 += __shfl_xor(aA1, 16); aA1 += __shfl_xor(aA1, 32);
    aA2 += __shfl_xor(aA2, 16); aA2 += __shfl_xor(aA2, 32);
    aA3 += __shfl_xor(aA3, 16); aA3 += __shfl_xor(aA3, 32);
    aB0 += __shfl_xor(aB0, 16); aB0 += __shfl_xor(aB0, 32);
    aB1 += __shfl_xor(aB1, 16); aB1 += __shfl_xor(aB1, 32);
    aB2 += __shfl_xor(aB2, 16); aB2 += __shfl_xor(aB2, 32);
    aB3 += __shfl_xor(aB3, 16); aB3 += __shfl_xor(aB3, 32);

    if (lane < 16) {
        float dmA = (float)(ndA > 1 ? ndA : 1);
        float dmB = (float)(ndB > 1 ? ndB : 1);
        ushort4 oA, oB;
        oA.x = f2bf(aA0 / dmA); oA.y = f2bf(aA1 / dmA);
        oA.z = f2bf(aA2 / dmA); oA.w = f2bf(aA3 / dmA);
        oB.x = f2bf(aB0 / dmB); oB.y = f2bf(aB1 / dmB);
        oB.z = f2bf(aB2 / dmB); oB.w = f2bf(aB3 / dmB);
        *(ushort4*)&aggL[wave][l16 * 4] = oA;
        *(ushort4*)&aggL[wave + 8][l16 * 4] = oB;
    }
    __syncthreads();

    // ---- phase 2: GEMM (waves 0-3; wave = col tile) ----
    if (wave < 4) {
        f32x4 acc = (f32x4){0.f, 0.f, 0.f, 0.f};
#pragma unroll
        for (int ki = 0; ki < 4; ++ki) {
            const ushort* ap = (ki < 2) ? &xL[l16][ki * 32 + g * 8]
                                        : &aggL[l16][(ki - 2) * 32 + g * 8];
            bf16x8 af = *(const bf16x8*)ap;
            bf16x8 bfrag = *(const bf16x8*)&Wb[(size_t)(wave * 16 + l16) * 128 + ki * 32 + g * 8];
            acc = __builtin_amdgcn_mfma_f32_16x16x32_bf16(af, bfrag, acc, 0, 0, 0);
        }
        int col = wave * 16 + l16;
        float bv = bias[col];
#pragma unroll
        for (int r = 0; r < 4; ++r) {
            int gn = nid[g * 4 + r];       // C/D: col=lane&15, row=quad*4+reg
            if (gn >= 0) {
                float v = fmaxf(acc[r] + bv, 0.f);
                if (out)  out[(size_t)gn * DD + col] = v;
                if (outb) outb[(size_t)gn * DD + col] = f2bf(v);
                if (outf8) {
                    unsigned int p = __builtin_amdgcn_cvt_pk_fp8_f32(v, v, 0u, false);
                    outf8[(size_t)gn * DD + col] = (unsigned char)(p & 0xFFu);
                }
            }
        }
    }
}

// ---------------------------------------------------------------------------
extern "C" void kernel_launch(void* const* d_in, const int* in_sizes, int n_in,
                              void* d_out, int out_size, void* d_ws, size_t ws_size,
                              hipStream_t stream)
{
    const float* x  = (const float*)d_in[0];
    const int*   ei = (const int*)d_in[1];
    const float* ew = (const float*)d_in[2];
    const float* W1 = (const float*)d_in[3];
    const float* b1 = (const float*)d_in[4];
    const float* W2 = (const float*)d_in[5];
    const float* b2 = (const float*)d_in[6];
    float* out = (float*)d_out;

    // workspace layout, ~53.5 MB (16B-aligned offsets)
    char* ws = (char*)d_ws;
    int*          gcur    = (int*)ws;                          //      8,192 B
    int*          gspillc = (int*)(ws + 8192);                 //      1,024 B
    int*          clsCnt  = (int*)(ws + 9216);                 //         64 B
    int*          perm    = (int*)(ws + 9280);                 //    213,568 B
    int2*         buf1    = (int2*)(ws + 222848);              // 16,777,216 B
    int2*         spill   = (int2*)(ws + 17000064);            //  1,048,576 B
    unsigned int* csr     = (unsigned int*)(ws + 18048640);    // 16,056,320 B (ELL 80/node)
    int*          cnt     = (int*)(ws + 34104960);             //    200,704 B
    ushort*       xb      = (ushort*)(ws + 34305664);          //  6,400,000 B
    ushort*       h1b     = (ushort*)(ws + 40705664);          //  6,400,000 B
    ushort*       W1b     = (ushort*)(ws + 47105664);          //     16,384 B
    ushort*       W2b     = (ushort*)(ws + 47122048);          //     16,384 B
    unsigned int* xf8     = (unsigned int*)(ws + 47138432);    //  3,200,000 B
    unsigned char* h1f8   = (unsigned char*)(ws + 50338432);   //  3,200,000 B

    hipMemsetAsync(gcur, 0, 9280, stream);             // gcur + gspillc + clsCnt
    hipMemsetAsync(perm, 0xFF, PSLOTS * 4, stream);    // perm = -1 sentinels

    prep_bin<<<NBLK + 3141, 256, 0, stream>>>(ei, ew, gcur, gspillc, buf1, spill,
                                              x, xb, xf8, W1, W2, W1b, W2b);
    build_ell<<<NBKT * 2, 1024, 0, stream>>>(gcur, buf1, gspillc, spill, csr, cnt,
                                             clsCnt, perm);

    // layer 1: gather fp8(x), self bf16(x) -> h1b + h1f8
    fused_layer<<<PSLOTS / 16, 512, 0, stream>>>(xb, xf8, cnt, csr, perm, W1b, b1,
                                                 nullptr, h1b, h1f8);
    // layer 2: gather fp8(h1), self bf16(h1) -> out
    fused_layer<<<PSLOTS / 16, 512, 0, stream>>>(h1b, (const unsigned int*)h1f8,
                                                 cnt, csr, perm, W2b, b2,
                                                 out, nullptr, nullptr);
}

// Round 6
// 172.404 us; speedup vs baseline: 3.3412x; 1.0958x over previous
//
#include <hip/hip_runtime.h>

#define NN 50000
#define NE 1600000
#define DD 64
#define NPB 196          // nodes per bucket
#define HPB 98           // nodes per build_ell half-bucket block
#define NBKT 256         // buckets (NPB*NBKT = 50176 >= NN)
#define CHUNK 2500       // edges per bin block (640 blocks * 2500 = NE)
#define NBLK 640
#define SLOT 24          // LDS records per bucket: lambda=9.77, +4.5 sigma
#define SSTR 25          // LDS stride pad (R12-proven)
#define S1CAP 1024       // per-(bucket,shard) region: lambda=781, +8.7 sigma
#define SPCAP 512        // per-bucket global spill region
#define ELLW 80          // fixed records per node row (pad-to-16); P(deg>80)~1e-12

typedef __attribute__((ext_vector_type(8))) short bf16x8;   // 8 bf16 = 4 VGPR
typedef __attribute__((ext_vector_type(4))) float f32x4;
typedef __attribute__((ext_vector_type(2))) float f32x2;

static __device__ __forceinline__ unsigned short f2bf(float f) {
    unsigned int u = __float_as_uint(f);
    unsigned int r = (u + 0x7FFFu + ((u >> 16) & 1u)) >> 16;   // RNE
    return (unsigned short)r;
}
static __device__ __forceinline__ float bf2f(unsigned short h) {
    return __uint_as_float((unsigned int)h << 16);
}
// pack 4 fp32 -> 4 x fp8-e4m3 (OCP, HW cvt)
static __device__ __forceinline__ unsigned int pk_fp8x4(float a, float b, float c, float d) {
    unsigned int p = __builtin_amdgcn_cvt_pk_fp8_f32(a, b, 0u, false);
    p = __builtin_amdgcn_cvt_pk_fp8_f32(c, d, p, true);
    return p;
}

// ---------------------------------------------------------------------------
// R15/R18 FUSED prep + binning (proven, in the 174.2us config).
// Blocks 0..639: LDS-staged edge binning. Blocks 640..3764: x cast.
// Blocks 3765..3780: W cast. gcur/gspillc zeroed by hipMemsetAsync before.
// Record: .x = dst(16) | w_bf16<<16, .y = node-within-bucket.
// ---------------------------------------------------------------------------
__global__ __launch_bounds__(256) void prep_bin(
    const int* __restrict__ ei, const float* __restrict__ ew,
    int* __restrict__ gcur, int* __restrict__ gspillc,
    int2* __restrict__ buf1, int2* __restrict__ spill,
    const float* __restrict__ x, ushort* __restrict__ xb,
    unsigned int* __restrict__ xf8,
    const float* __restrict__ W1, const float* __restrict__ W2,
    ushort* __restrict__ W1b, ushort* __restrict__ W2b)
{
    __shared__ int2 slot[NBKT * SSTR];   // 50 KB
    __shared__ int  lcnt[NBKT];
    __shared__ int  lbase[NBKT];
    int tid = threadIdx.x;
    int blk = blockIdx.x;

    if (blk >= NBLK) {
        int pb = blk - NBLK;
        if (pb < 3125) {                   // 3125*256 = 800000 = NN*DD/4
            int i = pb * 256 + tid;
            float4 v = ((const float4*)x)[i];
            ushort4 o;
            o.x = f2bf(v.x); o.y = f2bf(v.y); o.z = f2bf(v.z); o.w = f2bf(v.w);
            ((ushort4*)xb)[i] = o;
            xf8[i] = pk_fp8x4(v.x, v.y, v.z, v.w);
        } else {                           // 16*256 = 4096 float4 groups
            int i = (pb - 3125) * 256 + tid;
            const float* src = (i < 2048) ? W1 : W2;
            ushort* dst = (i < 2048) ? W1b : W2b;
            int j = i & 2047;
            float4 v = ((const float4*)src)[j];
            ushort4 o;
            o.x = f2bf(v.x); o.y = f2bf(v.y); o.z = f2bf(v.z); o.w = f2bf(v.w);
            ((ushort4*)dst)[j] = o;
        }
        return;
    }

    int shard = blk & 7;
    for (int b = tid; b < NBKT; b += 256) lcnt[b] = 0;
    __syncthreads();

    // 4-wide edge loads: CHUNK/4 = 625 int4-groups per block
    int g0 = blk * (CHUNK / 4);            // int4-group base
    const int4*   s4 = (const int4*)ei;            // src words
    const int4*   d4 = ((const int4*)ei) + NE / 4; // dst words
    const float4* w4 = (const float4*)ew;
    for (int it = 0; it < 3; ++it) {
        int idx = it * 256 + tid;
        if (idx >= CHUNK / 4) break;
        int4 sv = s4[g0 + idx];
        int4 dv = d4[g0 + idx];
        float4 wv = w4[g0 + idx];
#pragma unroll
        for (int k = 0; k < 4; ++k) {
            int s = (k == 0) ? sv.x : (k == 1) ? sv.y : (k == 2) ? sv.z : sv.w;
            int d = (k == 0) ? dv.x : (k == 1) ? dv.y : (k == 2) ? dv.z : dv.w;
            float w = (k == 0) ? wv.x : (k == 1) ? wv.y : (k == 2) ? wv.z : wv.w;
            int bkt = s / NPB;
            int sloc = s - bkt * NPB;
            int2 rec = make_int2(d | ((int)f2bf(w) << 16), sloc);
            int pos = atomicAdd(&lcnt[bkt], 1);
            if (pos < SLOT) {
                slot[bkt * SSTR + pos] = rec;
            } else {
                int sp = atomicAdd(&gspillc[bkt], 1);
                if (sp < SPCAP) spill[bkt * SPCAP + sp] = rec;
            }
        }
    }
    __syncthreads();

    // one global reservation per (block,bucket); tid==bucket (256==NBKT)
    {
        int b = tid;
        int n = lcnt[b]; if (n > SLOT) n = SLOT;
        lcnt[b] = n;
        lbase[b] = (n > 0) ? atomicAdd(&gcur[b * 8 + shard], n) : 0;
    }
    __syncthreads();

    // R18 flush: 16-lane group per bucket, 4 buckets per wave-iteration.
    int wave = tid >> 6, lane = tid & 63;
    int grp = lane >> 4, l16 = lane & 15;
#pragma unroll 4
    for (int jj = 0; jj < 16; ++jj) {
        int b = wave * 64 + jj * 4 + grp;
        int n = lcnt[b];
        int base = lbase[b];
        int2* dst = &buf1[((size_t)b * 8 + shard) * S1CAP];
        if (l16 < n) {
            int2 rec = slot[b * SSTR + l16];
            int p = base + l16;
            if (p < S1CAP) dst[p] = rec;
            else { int sp = atomicAdd(&gspillc[b], 1);
                   if (sp < SPCAP) spill[b * SPCAP + sp] = rec; }
        }
        if (l16 + 16 < n) {                 // n <= 24, so only lanes 0..7
            int2 rec = slot[b * SSTR + l16 + 16];
            int p = base + l16 + 16;
            if (p < S1CAP) dst[p] = rec;
            else { int sp = atomicAdd(&gspillc[b], 1);
                   if (sp < SPCAP) spill[b * SPCAP + sp] = rec; }
        }
    }
}

// ---------------------------------------------------------------------------
// R18 ELL build (proven, in the 174.2us config; perm machinery deleted).
// Grid 512 = 2 blocks per bucket (node-halves). Counts prefetched in
// parallel; 8 shards processed concurrently by 128-thread groups.
// Rows zero-padded deg..ceil16(deg) for fused_layer's uniform loop.
// ---------------------------------------------------------------------------
__global__ __launch_bounds__(1024) void build_ell(
    const int* __restrict__ gcur, const int2* __restrict__ buf1,
    const int* __restrict__ gspillc, const int2* __restrict__ spill,
    unsigned int* __restrict__ csr, int* __restrict__ cnt)
{
    __shared__ int cur[HPB];
    __shared__ int cnts[9];
    int tid = threadIdx.x;
    int bkt  = blockIdx.x >> 1;
    int nlo  = (blockIdx.x & 1) * HPB;      // this block owns nodes [nlo, nlo+98)

    if (tid < HPB) cur[tid] = 0;
    if (tid >= 128 && tid < 137) {          // parallel count prefetch
        int sh = tid - 128;
        int n = (sh < 8) ? gcur[bkt * 8 + sh] : gspillc[bkt];
        int cap = (sh < 8) ? S1CAP : SPCAP;
        cnts[sh] = n < cap ? n : cap;
    }
    __syncthreads();

    // 8 shards concurrently: 128 threads each
    {
        int sh = tid >> 7, lt = tid & 127;
        int n = cnts[sh];
        const int2* rp = buf1 + ((size_t)bkt * 8 + sh) * S1CAP;
        for (int i = lt; i < n; i += 128) {
            int2 r = rp[i];
            int node = r.y - nlo;
            if ((unsigned)node < HPB) {
                int pos = atomicAdd(&cur[node], 1);
                if (pos < ELLW)
                    csr[((size_t)(bkt * NPB + r.y)) * ELLW + pos] = (unsigned int)r.x;
            }
        }
    }
    // spill region: all threads
    {
        int n = cnts[8];
        const int2* rp = spill + (size_t)bkt * SPCAP;
        for (int i = tid; i < n; i += 1024) {
            int2 r = rp[i];
            int node = r.y - nlo;
            if ((unsigned)node < HPB) {
                int pos = atomicAdd(&cur[node], 1);
                if (pos < ELLW)
                    csr[((size_t)(bkt * NPB + r.y)) * ELLW + pos] = (unsigned int)r.x;
            }
        }
    }
    __syncthreads();

    if (tid < HPB) {
        int node = bkt * NPB + nlo + tid;
        if (node < NN) {
            int deg = cur[tid];
            cnt[node] = deg;
            int c = deg < ELLW ? deg : ELLW;
            int c16 = (c + 15) & ~15;          // <= 80 always
            for (int p = c; p < c16; ++p)
                csr[(size_t)node * ELLW + p] = 0u;
        }
    }
}

// processes one 16-record row chunk (uint4 r) for one node into packed accs
#define PROC16(r, s01, s23)                                                   \
    {                                                                         \
        unsigned int v0 = f8[(r.x & 0xFFFF) * 16 + l16];                      \
        unsigned int v1 = f8[(r.y & 0xFFFF) * 16 + l16];                      \
        unsigned int v2 = f8[(r.z & 0xFFFF) * 16 + l16];                      \
        unsigned int v3 = f8[(r.w & 0xFFFF) * 16 + l16];                      \
        float w0 = __uint_as_float(r.x & 0xFFFF0000u);                        \
        float w1 = __uint_as_float(r.y & 0xFFFF0000u);                        \
        float w2 = __uint_as_float(r.z & 0xFFFF0000u);                        \
        float w3 = __uint_as_float(r.w & 0xFFFF0000u);                        \
        f32x2 lo, hi, wp;                                                     \
        lo = __builtin_amdgcn_cvt_pk_f32_fp8(v0, false);                      \
        hi = __builtin_amdgcn_cvt_pk_f32_fp8(v0, true);                       \
        wp = (f32x2){w0, w0}; s01 += wp * lo; s23 += wp * hi;                 \
        lo = __builtin_amdgcn_cvt_pk_f32_fp8(v1, false);                      \
        hi = __builtin_amdgcn_cvt_pk_f32_fp8(v1, true);                       \
        wp = (f32x2){w1, w1}; s01 += wp * lo; s23 += wp * hi;                 \
        lo = __builtin_amdgcn_cvt_pk_f32_fp8(v2, false);                      \
        hi = __builtin_amdgcn_cvt_pk_f32_fp8(v2, true);                       \
        wp = (f32x2){w2, w2}; s01 += wp * lo; s23 += wp * hi;                 \
        lo = __builtin_amdgcn_cvt_pk_f32_fp8(v3, false);                      \
        hi = __builtin_amdgcn_cvt_pk_f32_fp8(v3, true);                       \
        wp = (f32x2){w3, w3}; s01 += wp * lo; s23 += wp * hi;                 \
    }

// ---------------------------------------------------------------------------
// R21 FUSED layer: R17 structure (512 thr, 8 waves, 16 sequential nodes,
// 2 per wave) + software-pipelined ELL-row prefetch: iteration i+16's row
// uint4s are loaded BEFORE iteration i is consumed, removing the row-load
// (L2/L3 ~200-400cy) from the per-iteration dependent chain. The chain is
// now gather-latency only, x2 independent node streams. Weight extract is
// a single AND (bf16<<16 == r & 0xFFFF0000). Packed f32x2 accumulators.
// Phase 2 (R7 layouts): waves 0-3 = one 16-col output tile, 4 MFMAs.
// ---------------------------------------------------------------------------
__global__ __launch_bounds__(512) void fused_layer(
    const ushort* __restrict__ Xb,          // self features bf16 [NN][64]
    const unsigned int* __restrict__ f8,    // gather table fp8, 16 uints/row
    const int* __restrict__ cnt, const unsigned int* __restrict__ csr,
    const ushort* __restrict__ Wb, const float* __restrict__ bias,
    float* __restrict__ out, ushort* __restrict__ outb,
    unsigned char* __restrict__ outf8)
{
    __shared__ ushort xL[16][72];
    __shared__ ushort aggL[16][72];
    int tid = threadIdx.x;
    int wave = tid >> 6, lane = tid & 63;   // wave in 0..7
    int g = lane >> 4, l16 = lane & 15;
    int base = blockIdx.x * 16;
    int nodeA = base + wave;                // tile rows 0..7
    int nodeB = base + wave + 8;            // tile rows 8..15

    // stage self rows (independent loads, issued early)
    if (lane < 16) {
        *(ushort4*)&xL[wave][l16 * 4] =
            *(const ushort4*)&Xb[(size_t)nodeA * DD + l16 * 4];
        *(ushort4*)&xL[wave + 8][l16 * 4] =
            *(const ushort4*)&Xb[(size_t)nodeB * DD + l16 * 4];
    }

    // ---- phase 1: aggregate two nodes per wave, pipelined ----
    int ndA = cnt[nodeA], ndB = cnt[nodeB];
    int nA = ndA < ELLW ? ndA : ELLW;
    int nB = ndB < ELLW ? ndB : ELLW;
    int nA16 = (nA + 15) & ~15;             // rows zero-padded to here
    int nB16 = (nB + 15) & ~15;
    int imax = nA16 > nB16 ? nA16 : nB16;
    const unsigned int* __restrict__ rpA = csr + (size_t)nodeA * ELLW + g * 4;
    const unsigned int* __restrict__ rpB = csr + (size_t)nodeB * ELLW + g * 4;
    f32x2 sA01 = {0.f, 0.f}, sA23 = {0.f, 0.f};
    f32x2 sB01 = {0.f, 0.f}, sB23 = {0.f, 0.f};

    // prologue: issue row 0 loads
    uint4 rA, rB;
    if (0 < nA16) rA = *(const uint4*)(rpA);
    if (0 < nB16) rB = *(const uint4*)(rpB);

    for (int i = 0; i < imax; i += 16) {
        // prefetch next iteration's rows (hidden under this iteration)
        uint4 rAn, rBn;
        bool doAn = (i + 16) < nA16, doBn = (i + 16) < nB16;
        if (doAn) rAn = *(const uint4*)(rpA + i + 16);
        if (doBn) rBn = *(const uint4*)(rpB + i + 16);
        bool doA = i < nA16, doB = i < nB16;
        if (doA) PROC16(rA, sA01, sA23);
        if (doB) PROC16(rB, sB01, sB23);
        rA = rAn; rB = rBn;
    }

    float aA0 = sA01.x, aA1 = sA01.y, aA2 = sA23.x, aA3 = sA23.y;
    float aB0 = sB01.x, aB1 = sB01.y, aB2 = sB23.x, aB3 = sB23.y;
    aA0 += __shfl_xor(aA0, 16); aA0 += __shfl_xor(aA0, 32);
    aA1 += __shfl_xor(aA1, 16); aA1 += __shfl_xor(aA1, 32);
    aA2 += __shfl_xor(aA2, 16); aA2 += __shfl_xor(aA2, 32);
    aA3 += __shfl_xor(aA3, 16); aA3 += __shfl_xor(aA3, 32);
    aB0 += __shfl_xor(aB0, 16); aB0 += __shfl_xor(aB0, 32);
    aB1 += __shfl_xor(aB1, 16); aB1 += __shfl_xor(aB1, 32);
    aB2 += __shfl_xor(aB2, 16); aB2 += __shfl_xor(aB2, 32);
    aB3 += __shfl_xor(aB3, 16); aB3 += __shfl_xor(aB3, 32);

    if (lane < 16) {
        float dmA = (float)(ndA > 1 ? ndA : 1);
        float dmB = (float)(ndB > 1 ? ndB : 1);
        ushort4 oA, oB;
        oA.x = f2bf(aA0 / dmA); oA.y = f2bf(aA1 / dmA);
        oA.z = f2bf(aA2 / dmA); oA.w = f2bf(aA3 / dmA);
        oB.x = f2bf(aB0 / dmB); oB.y = f2bf(aB1 / dmB);
        oB.z = f2bf(aB2 / dmB); oB.w = f2bf(aB3 / dmB);
        *(ushort4*)&aggL[wave][l16 * 4] = oA;
        *(ushort4*)&aggL[wave + 8][l16 * 4] = oB;
    }
    __syncthreads();

    // ---- phase 2: GEMM (waves 0-3; wave = col tile) ----
    if (wave < 4) {
        f32x4 acc = (f32x4){0.f, 0.f, 0.f, 0.f};
#pragma unroll
        for (int ki = 0; ki < 4; ++ki) {
            const ushort* ap = (ki < 2) ? &xL[l16][ki * 32 + g * 8]
                                        : &aggL[l16][(ki - 2) * 32 + g * 8];
            bf16x8 af = *(const bf16x8*)ap;
            bf16x8 bfrag = *(const bf16x8*)&Wb[(size_t)(wave * 16 + l16) * 128 + ki * 32 + g * 8];
            acc = __builtin_amdgcn_mfma_f32_16x16x32_bf16(af, bfrag, acc, 0, 0, 0);
        }
        int col = wave * 16 + l16;
        float bv = bias[col];
#pragma unroll
        for (int r = 0; r < 4; ++r) {
            int grow = base + g * 4 + r;   // C/D: col=lane&15, row=quad*4+reg
            float v = fmaxf(acc[r] + bv, 0.f);
            if (out)  out[(size_t)grow * DD + col] = v;
            if (outb) outb[(size_t)grow * DD + col] = f2bf(v);
            if (outf8) {
                unsigned int p = __builtin_amdgcn_cvt_pk_fp8_f32(v, v, 0u, false);
                outf8[(size_t)grow * DD + col] = (unsigned char)(p & 0xFFu);
            }
        }
    }
}

// ---------------------------------------------------------------------------
extern "C" void kernel_launch(void* const* d_in, const int* in_sizes, int n_in,
                              void* d_out, int out_size, void* d_ws, size_t ws_size,
                              hipStream_t stream)
{
    const float* x  = (const float*)d_in[0];
    const int*   ei = (const int*)d_in[1];
    const float* ew = (const float*)d_in[2];
    const float* W1 = (const float*)d_in[3];
    const float* b1 = (const float*)d_in[4];
    const float* W2 = (const float*)d_in[5];
    const float* b2 = (const float*)d_in[6];
    float* out = (float*)d_out;

    // workspace layout, ~53.3 MB (16B-aligned offsets)
    char* ws = (char*)d_ws;
    int*          gcur    = (int*)ws;                          //      8,192 B
    int*          gspillc = (int*)(ws + 8192);                 //      1,024 B
    int2*         buf1    = (int2*)(ws + 16384);               // 16,777,216 B
    int2*         spill   = (int2*)(ws + 16793600);            //  1,048,576 B
    unsigned int* csr     = (unsigned int*)(ws + 17842176);    // 16,056,320 B (ELL 80/node)
    int*          cnt     = (int*)(ws + 33898496);             //    200,704 B
    ushort*       xb      = (ushort*)(ws + 34099200);          //  6,400,000 B
    ushort*       h1b     = (ushort*)(ws + 40499200);          //  6,400,000 B
    ushort*       W1b     = (ushort*)(ws + 46899200);          //     16,384 B
    ushort*       W2b     = (ushort*)(ws + 46915584);          //     16,384 B
    unsigned int* xf8     = (unsigned int*)(ws + 46931968);    //  3,200,000 B
    unsigned char* h1f8   = (unsigned char*)(ws + 50131968);   //  3,200,000 B

    hipMemsetAsync(gcur, 0, 9216, stream);   // gcur + gspillc

    prep_bin<<<NBLK + 3141, 256, 0, stream>>>(ei, ew, gcur, gspillc, buf1, spill,
                                              x, xb, xf8, W1, W2, W1b, W2b);
    build_ell<<<NBKT * 2, 1024, 0, stream>>>(gcur, buf1, gspillc, spill, csr, cnt);

    // layer 1: gather fp8(x), self bf16(x) -> h1b + h1f8
    fused_layer<<<NN / 16, 512, 0, stream>>>(xb, xf8, cnt, csr, W1b, b1,
                                             nullptr, h1b, h1f8);
    // layer 2: gather fp8(h1), self bf16(h1) -> out
    fused_layer<<<NN / 16, 512, 0, stream>>>(h1b, (const unsigned int*)h1f8,
                                             cnt, csr, W2b, b2, out, nullptr, nullptr);
}